// Round 4
// baseline (224.602 us; speedup 1.0000x reference)
//
#include <hip/hip_runtime.h>

// Reference collapses: softmax over axis of size 1 == 1.0, so
// out[e] = sum_f h[edge_src[e], f].  W/b/leaky_relu/edge_dst are dead.
//
// Fused single persistent kernel:
//   phase 1: rowsum[n] = sum(h[n,:])   (grid-stride, 2 rows/wave, unroll x4)
//   device-scope grid barrier (all 1024 blocks co-resident by construction)
//   phase 2: out[e] = rowsum[esrc[e]]  (grid-stride, float4/int4, unroll x2)
// Barrier counter in d_ws, zeroed per call via hipMemsetAsync (capture-legal).

#define FDIM 128
#define NBLK 1024
#define BLOCK 256

__global__ __launch_bounds__(BLOCK, 4) void fused_kernel(
    const float4* __restrict__ h4, const int* __restrict__ esrc,
    float* __restrict__ rowsum, float* __restrict__ out,
    unsigned* __restrict__ bar, int N, int E) {
    const int lane = threadIdx.x & 63;
    const int half = lane >> 5;        // which row of the pair
    const int l32  = lane & 31;
    const int wave = (blockIdx.x * BLOCK + threadIdx.x) >> 6;
    const int nw   = (NBLK * BLOCK) >> 6;
    const int Pm   = N / 2;            // N = 100000 is even
    const int P    = (N + 1) / 2;

    // ---- phase 1: rowsum ----
    int i = wave;
    for (; i + 3 * nw < Pm; i += 4 * nw) {
        const int r0 = 2 * i + half;
        const int r1 = 2 * (i + nw) + half;
        const int r2 = 2 * (i + 2 * nw) + half;
        const int r3 = 2 * (i + 3 * nw) + half;
        const float4 v0 = h4[(size_t)r0 * 32 + l32];
        const float4 v1 = h4[(size_t)r1 * 32 + l32];
        const float4 v2 = h4[(size_t)r2 * 32 + l32];
        const float4 v3 = h4[(size_t)r3 * 32 + l32];
        float s0 = (v0.x + v0.y) + (v0.z + v0.w);
        float s1 = (v1.x + v1.y) + (v1.z + v1.w);
        float s2 = (v2.x + v2.y) + (v2.z + v2.w);
        float s3 = (v3.x + v3.y) + (v3.z + v3.w);
#pragma unroll
        for (int off = 16; off > 0; off >>= 1) {
            s0 += __shfl_xor(s0, off, 64);
            s1 += __shfl_xor(s1, off, 64);
            s2 += __shfl_xor(s2, off, 64);
            s3 += __shfl_xor(s3, off, 64);
        }
        if (l32 == 0) {
            rowsum[r0] = s0;
            rowsum[r1] = s1;
            rowsum[r2] = s2;
            rowsum[r3] = s3;
        }
    }
    for (; i < P; i += nw) {
        const int r = 2 * i + half;
        if (r < N) {
            const float4 v = h4[(size_t)r * 32 + l32];
            float s = (v.x + v.y) + (v.z + v.w);
#pragma unroll
            for (int off = 16; off > 0; off >>= 1) s += __shfl_xor(s, off, 64);
            if (l32 == 0) rowsum[r] = s;
        }
    }

    // ---- grid barrier (all NBLK blocks co-resident: 4 waves/block,
    //      launch_bounds(256,4) -> >=4 blocks/CU, NBLK = 4*256CU) ----
    __threadfence();               // release: rowsum visible device-wide
    __syncthreads();
    if (threadIdx.x == 0) {
        __hip_atomic_fetch_add(bar, 1u, __ATOMIC_ACQ_REL,
                               __HIP_MEMORY_SCOPE_AGENT);
        while (__hip_atomic_load(bar, __ATOMIC_ACQUIRE,
                                 __HIP_MEMORY_SCOPE_AGENT) < (unsigned)NBLK) {
            __builtin_amdgcn_s_sleep(1);
        }
    }
    __syncthreads();
    __threadfence();               // acquire: see other XCDs' rowsum

    // ---- phase 2: gather ----
    const int Q      = E / 4;
    const int t      = blockIdx.x * BLOCK + threadIdx.x;
    const int stride = NBLK * BLOCK;

    int q0 = t, q1 = t + stride;
    for (; q1 < Q; q0 += 2 * stride, q1 += 2 * stride) {
        const int4 ia = *reinterpret_cast<const int4*>(esrc + q0 * 4);
        const int4 ib = *reinterpret_cast<const int4*>(esrc + q1 * 4);
        float4 oa, ob;
        oa.x = rowsum[ia.x]; oa.y = rowsum[ia.y];
        oa.z = rowsum[ia.z]; oa.w = rowsum[ia.w];
        ob.x = rowsum[ib.x]; ob.y = rowsum[ib.y];
        ob.z = rowsum[ib.z]; ob.w = rowsum[ib.w];
        *reinterpret_cast<float4*>(out + q0 * 4) = oa;
        *reinterpret_cast<float4*>(out + q1 * 4) = ob;
    }
    for (; q0 < Q; q0 += stride) {
        const int4 ia = *reinterpret_cast<const int4*>(esrc + q0 * 4);
        float4 oa;
        oa.x = rowsum[ia.x]; oa.y = rowsum[ia.y];
        oa.z = rowsum[ia.z]; oa.w = rowsum[ia.w];
        *reinterpret_cast<float4*>(out + q0 * 4) = oa;
    }
    const int rem = Q * 4 + t;     // tail edges (E not multiple of 4)
    if (rem < E) out[rem] = rowsum[esrc[rem]];
}

extern "C" void kernel_launch(void* const* d_in, const int* in_sizes, int n_in,
                              void* d_out, int out_size, void* d_ws, size_t ws_size,
                              hipStream_t stream) {
    const float* h    = (const float*)d_in[0];   // [N, 128]
    const int*   esrc = (const int*)d_in[3];     // [E]
    float* out    = (float*)d_out;               // [E]
    float* rowsum = (float*)d_ws;                // [N] floats
    unsigned* bar = (unsigned*)((char*)d_ws + (1 << 20));  // 1 MB offset

    const int N = in_sizes[0] / FDIM;
    const int E = in_sizes[3];

    hipMemsetAsync(bar, 0, sizeof(unsigned), stream);
    fused_kernel<<<NBLK, BLOCK, 0, stream>>>(
        reinterpret_cast<const float4*>(h), esrc, rowsum, out, bar, N, E);
}

// Round 6
// 120.853 us; speedup vs baseline: 1.8585x; 1.8585x over previous
//
#include <hip/hip_runtime.h>

// Reference collapses: softmax over axis of size 1 == 1.0, so
// out[e] = sum_f h[edge_src[e], f].  W/b/leaky_relu/edge_dst are dead.
//
// Fused persistent kernel:
//   phase 1: rowsum[n] = sum(h[n,:])   (grid-stride, 2 rows/wave, unroll x4)
//   grid barrier: counter zeroed per call by hipMemsetAsync (capture-legal,
//     proven R3/R4); arrive with relaxed atomic add; spin on RELAXED atomic
//     load + s_sleep(16) (R4's 224us was acquire-per-poll invalidate storm);
//     single release fence before arrive, single acquire-ish fence after.
//   phase 2: out[e] = rowsum[esrc[e]]  (grid-stride, int4/float4, unroll x2)
// R5 deadlock root cause: ticket-round math without memset requires
// counter % NBLK == 0 at round start; 0xAA poison violates that.

#define FDIM 128
#define NBLK 512
#define BLOCK 256

__global__ __launch_bounds__(BLOCK, 4) void fused_kernel(
    const float4* __restrict__ h4, const int* __restrict__ esrc,
    float* __restrict__ rowsum, float* __restrict__ out,
    unsigned* __restrict__ bar, int N, int E) {
    const int lane = threadIdx.x & 63;
    const int half = lane >> 5;        // which row of the pair
    const int l32  = lane & 31;
    const int wave = (blockIdx.x * BLOCK + threadIdx.x) >> 6;
    const int nw   = (NBLK * BLOCK) >> 6;
    const int Pm   = N / 2;
    const int P    = (N + 1) / 2;

    // ---- phase 1: rowsum ----
    int i = wave;
    for (; i + 3 * nw < Pm; i += 4 * nw) {
        const int r0 = 2 * i + half;
        const int r1 = 2 * (i + nw) + half;
        const int r2 = 2 * (i + 2 * nw) + half;
        const int r3 = 2 * (i + 3 * nw) + half;
        const float4 v0 = h4[(size_t)r0 * 32 + l32];
        const float4 v1 = h4[(size_t)r1 * 32 + l32];
        const float4 v2 = h4[(size_t)r2 * 32 + l32];
        const float4 v3 = h4[(size_t)r3 * 32 + l32];
        float s0 = (v0.x + v0.y) + (v0.z + v0.w);
        float s1 = (v1.x + v1.y) + (v1.z + v1.w);
        float s2 = (v2.x + v2.y) + (v2.z + v2.w);
        float s3 = (v3.x + v3.y) + (v3.z + v3.w);
#pragma unroll
        for (int off = 16; off > 0; off >>= 1) {
            s0 += __shfl_xor(s0, off, 64);
            s1 += __shfl_xor(s1, off, 64);
            s2 += __shfl_xor(s2, off, 64);
            s3 += __shfl_xor(s3, off, 64);
        }
        if (l32 == 0) {
            rowsum[r0] = s0;
            rowsum[r1] = s1;
            rowsum[r2] = s2;
            rowsum[r3] = s3;
        }
    }
    for (; i < P; i += nw) {
        const int r = 2 * i + half;
        if (r < N) {
            const float4 v = h4[(size_t)r * 32 + l32];
            float s = (v.x + v.y) + (v.z + v.w);
#pragma unroll
            for (int off = 16; off > 0; off >>= 1) s += __shfl_xor(s, off, 64);
            if (l32 == 0) rowsum[r] = s;
        }
    }

    // ---- grid barrier (512 blocks, 4 waves each; VGPR=24 -> 8 blocks/CU
    //      capacity, 4x co-residency margin -> cannot deadlock) ----
    __threadfence();                         // release rowsum device-wide
    __syncthreads();
    if (threadIdx.x == 0) {
        __hip_atomic_fetch_add(bar, 1u, __ATOMIC_RELAXED,
                               __HIP_MEMORY_SCOPE_AGENT);
        while (__hip_atomic_load(bar, __ATOMIC_RELAXED,
                                 __HIP_MEMORY_SCOPE_AGENT) < (unsigned)NBLK) {
            __builtin_amdgcn_s_sleep(16);    // ~1024 cy between polls
        }
    }
    __syncthreads();
    __threadfence();                         // acquire: see remote rowsum

    // ---- phase 2: gather ----
    const int Q      = E / 4;
    const int t      = blockIdx.x * BLOCK + threadIdx.x;
    const int stride = NBLK * BLOCK;

    int q0 = t, q1 = t + stride;
    for (; q1 < Q; q0 += 2 * stride, q1 += 2 * stride) {
        const int4 ia = *reinterpret_cast<const int4*>(esrc + q0 * 4);
        const int4 ib = *reinterpret_cast<const int4*>(esrc + q1 * 4);
        float4 oa, ob;
        oa.x = rowsum[ia.x]; oa.y = rowsum[ia.y];
        oa.z = rowsum[ia.z]; oa.w = rowsum[ia.w];
        ob.x = rowsum[ib.x]; ob.y = rowsum[ib.y];
        ob.z = rowsum[ib.z]; ob.w = rowsum[ib.w];
        *reinterpret_cast<float4*>(out + q0 * 4) = oa;
        *reinterpret_cast<float4*>(out + q1 * 4) = ob;
    }
    for (; q0 < Q; q0 += stride) {
        const int4 ia = *reinterpret_cast<const int4*>(esrc + q0 * 4);
        float4 oa;
        oa.x = rowsum[ia.x]; oa.y = rowsum[ia.y];
        oa.z = rowsum[ia.z]; oa.w = rowsum[ia.w];
        *reinterpret_cast<float4*>(out + q0 * 4) = oa;
    }
    const int rem = Q * 4 + t;               // tail (E not multiple of 4)
    if (rem < E) out[rem] = rowsum[esrc[rem]];
}

extern "C" void kernel_launch(void* const* d_in, const int* in_sizes, int n_in,
                              void* d_out, int out_size, void* d_ws, size_t ws_size,
                              hipStream_t stream) {
    const float* h    = (const float*)d_in[0];   // [N, 128]
    const int*   esrc = (const int*)d_in[3];     // [E]
    float* out    = (float*)d_out;               // [E]
    float* rowsum = (float*)d_ws;                // [N] floats
    unsigned* bar = (unsigned*)((char*)d_ws + (1 << 20));  // 1 MB offset

    const int N = in_sizes[0] / FDIM;
    const int E = in_sizes[3];

    hipMemsetAsync(bar, 0, sizeof(unsigned), stream);
    fused_kernel<<<NBLK, BLOCK, 0, stream>>>(
        reinterpret_cast<const float4*>(h), esrc, rowsum, out, bar, N, E);
}